// Round 11
// baseline (1171.850 us; speedup 1.0000x reference)
//
#include <hip/hip_runtime.h>

typedef unsigned short u16;
typedef unsigned int u32;

__device__ __forceinline__ float b2f(u16 v) { return __uint_as_float((u32)v << 16); }
__device__ __forceinline__ float lopart(u32 u) { return __uint_as_float(u << 16); }
__device__ __forceinline__ float hipart(u32 u) { return __uint_as_float(u & 0xffff0000u); }
__device__ __forceinline__ u16 f2b(float f) {
  u32 u = __float_as_uint(f);
  u32 r = u + 0x7fffu + ((u >> 16) & 1u);
  return (u16)(r >> 16);
}
__device__ __forceinline__ u32 pk2(float a, float b) {
  return (u32)f2b(a) | ((u32)f2b(b) << 16);
}

struct Ptrs { const void* p[29]; };

typedef __attribute__((ext_vector_type(8))) short short8;
typedef __attribute__((ext_vector_type(4))) float floatx4;

// ---------------- K-2: dtype flag (bn1_g[0]: bf16 pair 0x3F803F80 vs fp32 0x3F800000) ----------------
__global__ void k_resolve(const void* __restrict__ g1, int* __restrict__ dtf) {
  if (threadIdx.x == 0) {
    u32 w = *(const u32*)g1;
    *dtf = ((w & 0xffffu) != 0) ? 1 : 0;
  }
}

// ---------------- K-1: convert A + all weights to fp32 (C-order identity; dict order) ----------------
__global__ __launch_bounds__(256) void k_cvt(Ptrs ps, const int* __restrict__ dtf,
                                             float* __restrict__ Af, float* __restrict__ Wf) {
  bool BF = *dtf != 0;
  int i = blockIdx.x * 256 + threadIdx.x;
  if (i < 250000) {
    const void* pA = ps.p[1];
    Af[i] = BF ? b2f(((const u16*)pA)[i]) : ((const float*)pA)[i];
    return;
  }
  int j = i - 250000;
  if (j >= 65322) return;
  const int SZ[27] = {1024,32,2048,64,12288,64,12288,64,4096,64,4096,64,2048,32,
                      10240,64,60,6,32,500,16000,36,36,6,6,32,32};
  int t = 0, off = 0;
#pragma unroll
  for (int k = 0; k < 27; ++k) {
    if (t == k && j >= off + SZ[k]) { off += SZ[k]; t = k + 1; }
  }
  const void* src = ps.p[2 + t];
  int l = j - off;
  Wf[j] = BF ? b2f(((const u16*)src)[l]) : ((const float*)src)[l];
}

// ---------------- K-0b: x -> fp32 (identity C-order) ----------------
__global__ __launch_bounds__(256) void k_cvtx(const void* __restrict__ x, const int* __restrict__ dtf,
                                              float* __restrict__ xf) {
  bool BF = *dtf != 0;
  int i = blockIdx.x * 256 + threadIdx.x;
  if (i < 2560000) xf[i] = BF ? b2f(((const u16*)x)[i]) : ((const float*)x)[i];
}

// ---------------- K0: A2 = A @ A  (fp32) ----------------
__global__ __launch_bounds__(256) void k_a2(const float* __restrict__ Af, float* __restrict__ A2) {
  __shared__ float Arow[8][500];
  int tid = threadIdx.x;
  int j = blockIdx.x * 256 + tid;
  int i0 = blockIdx.y * 8;
  for (int i = tid; i < 4000; i += 256) {
    int r = i / 500, kk = i - r * 500;
    int ii = i0 + r; if (ii > 499) ii = 499;
    Arow[r][kk] = Af[ii * 500 + kk];
  }
  __syncthreads();
  if (j >= 500) return;
  float acc[8];
#pragma unroll
  for (int ii = 0; ii < 8; ++ii) acc[ii] = 0.f;
  for (int k = 0; k < 500; ++k) {
    float akj = Af[k * 500 + j];
#pragma unroll
    for (int ii = 0; ii < 8; ++ii) acc[ii] += Arow[ii][k] * akj;
  }
#pragma unroll
  for (int ii = 0; ii < 8; ++ii)
    if (i0 + ii < 500) A2[(i0 + ii) * 500 + j] = acc[ii];
}

// ---------------- K0b: pack A, A2 to zero-padded 512x512 bf16 ----------------
__global__ __launch_bounds__(256) void k_pk(const float* __restrict__ Af, const float* __restrict__ A2,
                                            u16* __restrict__ Abf, u16* __restrict__ A2bf) {
  int i = blockIdx.x * 256 + threadIdx.x;
  if (i >= 262144) return;
  int r = i >> 9, v = i & 511;
  bool in = (r < 500) && (v < 500);
  Abf[i]  = f2b(in ? Af[r * 500 + v] : 0.f);
  A2bf[i] = f2b(in ? A2[r * 500 + v] : 0.f);
}

// ---------------- K0c: pack frontend weights coalesced-by-o (into dead A2 region) ----------------
__global__ __launch_bounds__(256) void k_wpack(
    const float* __restrict__ qW, const float* __restrict__ kW,
    const float* __restrict__ te1W, const float* __restrict__ lvW,
    const float* __restrict__ loW, const float* __restrict__ te2W, const float* __restrict__ c1W,
    u32* __restrict__ qkp, float* __restrict__ te1T, float* __restrict__ lvT,
    float* __restrict__ loT, float* __restrict__ te2T, float* __restrict__ c1T) {
  int i = blockIdx.x * 256 + threadIdx.x;
  if (i < 12288) {
    int ii = i / 192, r = i - ii * 192, tap = r >> 6, o = r & 63;
    int si = o * 192 + ii * 3 + tap;
    qkp[i] = pk2(qW[si], kW[si]);
    return;
  }
  int j = i - 12288;
  if (j < 2048) { int c = j >> 6, o = j & 63; te1T[j] = te1W[o * 32 + c]; return; }
  j -= 2048;
  if (j < 4096) { int ii = j >> 6, o = j & 63; lvT[j] = lvW[o * 64 + ii]; return; }
  j -= 4096;
  if (j < 4096) { int jj = j >> 6, o = j & 63; loT[j] = loW[o * 64 + jj]; return; }
  j -= 4096;
  if (j < 2048) { int jj = j >> 5, c = j & 31; te2T[j] = te2W[c * 64 + jj]; return; }
  j -= 2048;
  if (j < 1024) { int ii = j >> 5, c = j & 31; c1T[j] = c1W[c * 32 + ii]; return; }
}

// ---------------- K1: frontend  x -> h3x (B,T,N,32) + res6 ----------------
// Low-LDS (~15 KB) high-occupancy version: weights from L2-hot packed global arrays,
// lane mapping (o = tid&63, tg = tid>>6, t in {tg, tg+4, tg+8}) -> coalesced weight
// reads shared across 3 t's, wave-uniform h1/xv broadcasts. 4 n per block.
__global__ __launch_bounds__(256) void k_front(
    const float* __restrict__ xf, const u32* __restrict__ qkp,
    const float* __restrict__ te1T, const float* __restrict__ lvT,
    const float* __restrict__ loT, const float* __restrict__ te2T,
    const float* __restrict__ c1T,
    const float* __restrict__ c1B, const float* __restrict__ te1B,
    const float* __restrict__ qB, const float* __restrict__ kB,
    const float* __restrict__ lvB, const float* __restrict__ loB,
    const float* __restrict__ te2B,
    float* __restrict__ h3x, float* __restrict__ res6)
{
  __shared__ float xv[4][32][10];
  __shared__ float h1b[64][10];
  __shared__ float qbuf[64][10];
  __shared__ float kbuf[64][10];
  __shared__ float vbuf[64][10];
  __shared__ float scb[800];
  int tid = threadIdx.x;
  int b = blockIdx.y;
  int n0 = blockIdx.x * 4;
  for (int i = tid; i < 1280; i += 256) {
    int nl = i / 320, r = i - nl * 320, c = r / 10, t = r - c * 10;
    xv[nl][c][t] = xf[((b * 32 + c) * 500 + n0 + nl) * 10 + t];
  }
  __syncthreads();
  // res6 for all 4 n (reads xv only)
  for (int i = tid; i < 768; i += 256) {
    int nl = i / 192, r = i - nl * 192;
    int c = r & 31, t6 = r >> 5;
    float a = c1B[c];
    for (int ii = 0; ii < 32; ++ii) a += c1T[ii * 32 + c] * xv[nl][ii][t6 + 4];
    res6[((b * 32 + c) * 500 + n0 + nl) * 6 + t6] = a;
  }
  int o = tid & 63, tg = tid >> 6;
  for (int nl = 0; nl < 4; ++nl) {
    // h1 = te1(x)
    {
      float a[3];
#pragma unroll
      for (int m = 0; m < 3; ++m) a[m] = te1B[o];
      for (int c = 0; c < 32; ++c) {
        float w = te1T[c * 64 + o];
#pragma unroll
        for (int m = 0; m < 3; ++m) {
          int t = tg + 4 * m;
          if (t < 10) a[m] += w * xv[nl][c][t];
        }
      }
#pragma unroll
      for (int m = 0; m < 3; ++m) { int t = tg + 4 * m; if (t < 10) h1b[o][t] = a[m]; }
    }
    __syncthreads();
    // q,k (T-conv) and v
    {
      float aq[3], ak[3], av[3];
#pragma unroll
      for (int m = 0; m < 3; ++m) { aq[m] = qB[o]; ak[m] = kB[o]; av[m] = lvB[o]; }
      for (int i = 0; i < 64; ++i) {
        u32 u0 = qkp[i * 192 + o], u1 = qkp[i * 192 + 64 + o], u2 = qkp[i * 192 + 128 + o];
        float lw = lvT[i * 64 + o];
#pragma unroll
        for (int m = 0; m < 3; ++m) {
          int t = tg + 4 * m;
          if (t < 10) {
            float hm = (t > 0) ? h1b[i][t - 1] : 0.f;
            float h0 = h1b[i][t];
            float hp = (t < 9) ? h1b[i][t + 1] : 0.f;
            aq[m] += lopart(u0) * hm + lopart(u1) * h0 + lopart(u2) * hp;
            ak[m] += hipart(u0) * hm + hipart(u1) * h0 + hipart(u2) * hp;
            av[m] += lw * h0;
          }
        }
      }
#pragma unroll
      for (int m = 0; m < 3; ++m) {
        int t = tg + 4 * m;
        if (t < 10) { qbuf[o][t] = aq[m]; kbuf[o][t] = ak[m]; vbuf[o][t] = av[m]; }
      }
    }
    __syncthreads();
    // scores
    for (int idx = tid; idx < 800; idx += 256) {
      int h = idx / 100, r = (idx / 10) % 10, s = idx - (idx / 10) * 10;
      float a = 0.f;
#pragma unroll
      for (int d = 0; d < 8; ++d) a += qbuf[h * 8 + d][r] * kbuf[h * 8 + d][s];
      scb[idx] = a * 0.35355339059327373f;
    }
    __syncthreads();
    // softmax rows (80 rows of 10)
    if (tid < 80) {
      float* row = scb + tid * 10;
      float mx = row[0];
#pragma unroll
      for (int s = 1; s < 10; ++s) mx = fmaxf(mx, row[s]);
      float tot = 0.f;
#pragma unroll
      for (int s = 0; s < 10; ++s) { float e2 = expf(row[s] - mx); row[s] = e2; tot += e2; }
      float inv = 1.f / tot;
#pragma unroll
      for (int s = 0; s < 10; ++s) row[s] *= inv;
    }
    __syncthreads();
    // o = p @ v (into qbuf; q's readers finished at scores barrier)
    {
      int h = o >> 3;
      float a[3] = {0.f, 0.f, 0.f};
#pragma unroll
      for (int m = 0; m < 3; ++m) {
        int t = tg + 4 * m;
        if (t < 10) {
          float s = 0.f;
#pragma unroll
          for (int ss = 0; ss < 10; ++ss) s += scb[h * 100 + t * 10 + ss] * vbuf[o][ss];
          a[m] = s;
        }
      }
#pragma unroll
      for (int m = 0; m < 3; ++m) { int t = tg + 4 * m; if (t < 10) qbuf[o][t] = a[m]; }
    }
    __syncthreads();
    // h2 = lino(o) (into kbuf; k's readers finished at scores barrier)
    {
      float a[3];
#pragma unroll
      for (int m = 0; m < 3; ++m) a[m] = loB[o];
      for (int j = 0; j < 64; ++j) {
        float w = loT[j * 64 + o];
#pragma unroll
        for (int m = 0; m < 3; ++m) { int t = tg + 4 * m; if (t < 10) a[m] += w * qbuf[j][t]; }
      }
#pragma unroll
      for (int m = 0; m < 3; ++m) { int t = tg + 4 * m; if (t < 10) kbuf[o][t] = a[m]; }
    }
    __syncthreads();
    // h3 = te2(h2) -> h3x (B,T,N,32)
    {
      int c = tid & 31, tg8 = tid >> 5;
      float a0 = te2B[c], a1 = te2B[c];
      bool hi2 = (tg8 + 8) < 10;
      for (int j = 0; j < 64; ++j) {
        float w = te2T[j * 32 + c];
        a0 += w * kbuf[j][tg8];
        if (hi2) a1 += w * kbuf[j][tg8 + 8];
      }
      h3x[((b * 10 + tg8) * 500 + n0 + nl) * 32 + c] = a0;
      if (hi2) h3x[((b * 10 + tg8 + 8) * 500 + n0 + nl) * 32 + c] = a1;
    }
    __syncthreads();
  }
}

// ---------------- K2: MFMA z1 = A @ XT, z2 = A2 @ XT ----------------
__global__ __launch_bounds__(256, 4) void k_z12m(const float* __restrict__ h3x,
    const u16* __restrict__ Abf, const u16* __restrict__ A2bf,
    float* __restrict__ z1x, float* __restrict__ z2x) {
  __shared__ u32 xlsT[8192];     // [n][half-row] pairs, swizzled (32 KB)
  int tid = threadIdx.x, bt = blockIdx.x;
  const float* src = h3x + bt * 16000;
  for (int i = tid; i < 8192; i += 256) {
    int n = i & 31, h = i >> 5;
    int r0 = 2 * h;
    float v0 = (r0 < 500) ? src[r0 * 32 + n] : 0.f;
    float v1 = (r0 + 1 < 500) ? src[(r0 + 1) * 32 + n] : 0.f;
    xlsT[n * 256 + (((h & 0xFC) ^ ((n & 15) << 2)) | (h & 3))] = pk2(v0, v1);
  }
  __syncthreads();
  int lane = tid & 63, wave = tid >> 6;
  int q = lane >> 4, ln = lane & 15;
  int rbase = blockIdx.y * 64 + wave * 16;
  const u32* Au = (const u32*)Abf;
  const u32* A2u = (const u32*)A2bf;
  int arow = (rbase + ln) * 256;
  union F8 { u32 u[4]; short8 s; };
  floatx4 acc1[2] = {{0.f,0.f,0.f,0.f},{0.f,0.f,0.f,0.f}};
  floatx4 acc2[2] = {{0.f,0.f,0.f,0.f},{0.f,0.f,0.f,0.f}};
  for (int c2 = 0; c2 < 16; ++c2) {
    int hb = c2 * 16 + q * 4;
    F8 a1f, a2f;
#pragma unroll
    for (int i2 = 0; i2 < 4; ++i2) {
      a1f.u[i2] = Au[arow + hb + i2];
      a2f.u[i2] = A2u[arow + hb + i2];
    }
#pragma unroll
    for (int t2 = 0; t2 < 2; ++t2) {
      int n = t2 * 16 + ln;
      int baseT = n * 256 + (hb ^ ((n & 15) << 2));
      F8 bf;
#pragma unroll
      for (int i2 = 0; i2 < 4; ++i2) bf.u[i2] = xlsT[baseT + i2];
      acc1[t2] = __builtin_amdgcn_mfma_f32_16x16x32_bf16(a1f.s, bf.s, acc1[t2], 0, 0, 0);
      acc2[t2] = __builtin_amdgcn_mfma_f32_16x16x32_bf16(a2f.s, bf.s, acc2[t2], 0, 0, 0);
    }
  }
  int outb = bt * 16000;
#pragma unroll
  for (int t2 = 0; t2 < 2; ++t2) {
#pragma unroll
    for (int i2 = 0; i2 < 4; ++i2) {
      int r = rbase + q * 4 + i2;
      if (r < 500) {
        z1x[outb + r * 32 + t2 * 16 + ln] = acc1[t2][i2];
        z2x[outb + r * 32 + t2 * 16 + ln] = acc2[t2][i2];
      }
    }
  }
}

// ---------------- K3: MFMA fused attention: out = softmax(K K^T / sqrt(32)) @ V ----------------
__global__ __launch_bounds__(256, 2) void k_attn2(const float* __restrict__ keys,
                                                  const float* __restrict__ vals,
                                                  float* __restrict__ outp) {
  __shared__ u32 xls[8192];        // 512 rows x 16 u32 bf16-pairs, swizzled (32 KB)
  __shared__ u32 pch[4][272];      // per-wave P chunk: 16 x 17 u32 (4.25 KB)
  int tid = threadIdx.x, bt = blockIdx.x;
  const float* kb = keys + bt * 16000;
  for (int i = tid; i < 8192; i += 256) {
    int r = i >> 4, cu = i & 15;
    u32 u = 0;
    if (r < 500) {
      float2 g = *(const float2*)(kb + r * 32 + cu * 2);
      u = pk2(g.x, g.y);
    }
    xls[(r << 4) | (cu ^ (r & 15))] = u;
  }
  __syncthreads();
  int lane = tid & 63, wave = tid >> 6;
  int q = lane >> 4, ln = lane & 15;
  int rbase = blockIdx.y * 64 + wave * 16;
  union F8 { u32 u[4]; short8 s; };
  F8 af;
  {
    int r = rbase + ln;
#pragma unroll
    for (int i2 = 0; i2 < 4; ++i2)
      af.u[i2] = xls[(r << 4) | ((q * 4 + i2) ^ (r & 15))];
  }
  floatx4 acc[32];
#pragma unroll
  for (int ct = 0; ct < 32; ++ct) {
    int r2 = ct * 16 + ln;
    F8 bf;
#pragma unroll
    for (int i2 = 0; i2 < 4; ++i2)
      bf.u[i2] = xls[(r2 << 4) | ((q * 4 + i2) ^ (r2 & 15))];
    acc[ct] = __builtin_amdgcn_mfma_f32_16x16x32_bf16(af.s, bf.s,
              (floatx4){0.f, 0.f, 0.f, 0.f}, 0, 0, 0);
  }
  if (ln >= 4) {
#pragma unroll
    for (int i2 = 0; i2 < 4; ++i2) acc[31][i2] = -1e30f;
  }
  const float sc = 0.17677669529663687f;
  float inv[4];
#pragma unroll
  for (int i2 = 0; i2 < 4; ++i2) {
    float m = -1e30f;
#pragma unroll
    for (int ct = 0; ct < 32; ++ct) m = fmaxf(m, acc[ct][i2]);
#pragma unroll
    for (int d = 1; d < 16; d <<= 1) m = fmaxf(m, __shfl_xor(m, d));
    float s = 0.f;
#pragma unroll
    for (int ct = 0; ct < 32; ++ct) {
      float e = expf((acc[ct][i2] - m) * sc);
      acc[ct][i2] = e; s += e;
    }
#pragma unroll
    for (int d = 1; d < 16; d <<= 1) s += __shfl_xor(s, d);
    inv[i2] = 1.f / s;
  }
  const float* vb = vals + bt * 16000;
  floatx4 zacc[2] = {{0.f,0.f,0.f,0.f},{0.f,0.f,0.f,0.f}};
  u32* myp = pch[wave];
  u16* pw = (u16*)myp;
  for (int c2 = 0; c2 < 16; ++c2) {
#pragma unroll
    for (int t2 = 0; t2 < 2; ++t2) {
      int ct = c2 * 2 + t2;
#pragma unroll
      for (int i2 = 0; i2 < 4; ++i2)
        pw[(q * 4 + i2) * 34 + t2 * 16 + ln] = f2b(acc[ct][i2] * inv[i2]);
    }
    __syncthreads();
    F8 pa;
#pragma unroll
    for (int i2 = 0; i2 < 4; ++i2) pa.u[i2] = myp[ln * 17 + q * 4 + i2];
    int k0 = c2 * 32 + q * 8;
#pragma unroll
    for (int t2 = 0; t2 < 2; ++t2) {
      int n = t2 * 16 + ln;
      short8 bs;
#pragma unroll
      for (int j = 0; j < 8; ++j) {
        float v = vb[(k0 + j) * 32 + n];
        bs[j] = (short)(__float_as_uint(v) >> 16);
      }
      zacc[t2] = __builtin_amdgcn_mfma_f32_16x16x32_bf16(pa.s, bs, zacc[t2], 0, 0, 0);
    }
    __syncthreads();
  }
  int outb = bt * 16000;
#pragma unroll
  for (int t2 = 0; t2 < 2; ++t2) {
#pragma unroll
    for (int i2 = 0; i2 < 4; ++i2) {
      int r = rbase + q * 4 + i2;
      if (r < 500) outp[outb + r * 32 + t2 * 16 + ln] = zacc[t2][i2];
    }
  }
}

// ---------------- K4: mlp + gate + ct1 -> g2 ----------------
__global__ __launch_bounds__(256) void k_mlp(
    const float* __restrict__ h3x, const float* __restrict__ z1x, const float* __restrict__ z2x,
    const float* __restrict__ z3x, const float* __restrict__ z4x,
    const float* __restrict__ mlpW, const float* __restrict__ mlpB,
    const float* __restrict__ ct1W, const float* __restrict__ ct1B,
    float* __restrict__ g2w)
{
  __shared__ float Wm[10240];
  __shared__ float cat[32][161];
  __shared__ float ct1l[60];
  __shared__ float ct1bl[6];
  __shared__ float mbl[64];
  int tid = threadIdx.x;
  int b = blockIdx.y, n0 = blockIdx.x * 32;
  int nn = 500 - n0; if (nn > 32) nn = 32;
  for (int i = tid; i < 10240; i += 256) Wm[i] = mlpW[i];
  if (tid < 60) ct1l[tid] = ct1W[tid];
  if (tid < 6)  ct1bl[tid] = ct1B[tid];
  if (tid < 64) mbl[tid] = mlpB[tid];
  __syncthreads();
  int nl = tid & 31, slot = tid >> 5;
  bool act = nl < nn;
  int n = n0 + nl;
  float g2r[4][6];
#pragma unroll
  for (int k = 0; k < 4; ++k)
#pragma unroll
    for (int s = 0; s < 6; ++s) g2r[k][s] = 0.f;
  for (int t = 0; t < 10; ++t) {
    int rowbase = (b * 10 + t) * 500 + n0;
#pragma unroll
    for (int seg = 0; seg < 5; ++seg) {
      const float* sp = seg == 0 ? h3x : seg == 1 ? z1x : seg == 2 ? z2x : seg == 3 ? z3x : z4x;
      for (int i = tid; i < 1024; i += 256) {
        int nb = i >> 5, cc = i & 31;
        cat[nb][seg * 32 + cc] = (nb < nn) ? sp[(rowbase + nb) * 32 + cc] : 0.f;
      }
    }
    __syncthreads();
    if (act) {
      float hc[8];
#pragma unroll
      for (int k = 0; k < 8; ++k) hc[k] = mbl[slot + 8 * k];
      for (int cch = 0; cch < 160; ++cch) {
        float xvv = cat[nl][cch];
#pragma unroll
        for (int k = 0; k < 8; ++k) hc[k] += Wm[(slot + 8 * k) * 160 + cch] * xvv;
      }
#pragma unroll
      for (int k = 0; k < 4; ++k) {
        float gk = tanhf(hc[k]) * (1.f / (1.f + expf(-hc[k + 4])));
#pragma unroll
        for (int s = 0; s < 6; ++s) g2r[k][s] += gk * ct1l[s * 10 + t];
      }
    }
    __syncthreads();
  }
  if (act) {
#pragma unroll
    for (int k = 0; k < 4; ++k) {
      int cc = slot + 8 * k;
      int base = ((b * 32 + cc) * 500 + n) * 6;
#pragma unroll
      for (int s = 0; s < 6; ++s) g2w[base + s] = g2r[k][s] + ct1bl[s];
    }
  }
}

// ---------------- K4b: f1 ----------------
__global__ __launch_bounds__(256) void k_f1n(const float* __restrict__ g2w,
                                             const float* __restrict__ tc1W,
                                             float* __restrict__ f1w) {
  int i = blockIdx.x * 256 + threadIdx.x;
  if (i >= 48000) return;
  int b = i / 3000, rem = i - b * 3000, s = rem / 500, n = rem - s * 500;
  float a = 0.f;
  for (int c = 0; c < 32; ++c) a += g2w[((b * 32 + c) * 500 + n) * 6 + s] * tc1W[c];
  f1w[(b * 6 + s) * 500 + n] = a;
}

// ---------------- K5a: f2 ----------------
__global__ __launch_bounds__(64) void k_f2(const float* __restrict__ g2w,
                                           const float* __restrict__ c2W, float* __restrict__ f2w) {
  int b = blockIdx.x >> 5, c = blockIdx.x & 31, lane = threadIdx.x;
  float acc[6];
#pragma unroll
  for (int t = 0; t < 6; ++t) acc[t] = 0.f;
  for (int n = lane; n < 500; n += 64) {
    float w = c2W[n];
    const float* gp = g2w + ((b * 32 + c) * 500 + n) * 6;
#pragma unroll
    for (int t = 0; t < 6; ++t) acc[t] += w * gp[t];
  }
#pragma unroll
  for (int t = 0; t < 6; ++t)
    for (int off = 32; off; off >>= 1) acc[t] += __shfl_xor(acc[t], off);
  if (lane == 0) {
#pragma unroll
    for (int t = 0; t < 6; ++t) f2w[(b * 32 + c) * 6 + t] = acc[t];
  }
}

// ---------------- K5b: per-b TATT ----------------
__global__ __launch_bounds__(256) void k_tatt(
    const float* __restrict__ f1w, const float* __restrict__ tatw,
    const float* __restrict__ f2w, const float* __restrict__ tatb, const float* __restrict__ tatv,
    float* __restrict__ lg2w)
{
  __shared__ float mid[192];
  __shared__ float lgt[36];
  int b = blockIdx.x, tid = threadIdx.x;
  if (tid < 192) {
    int t = tid >> 5, c = tid & 31;
    float a = 0.f;
    const float* f1p = f1w + (b * 6 + t) * 500;
    for (int n = 0; n < 500; ++n) a += f1p[n] * tatw[n * 32 + c];
    mid[t * 32 + c] = a;
  }
  __syncthreads();
  if (tid < 36) {
    int t = tid / 6, s = tid - t * 6;
    float a = tatb[t * 6 + s];
    for (int c = 0; c < 32; ++c) a += mid[t * 32 + c] * f2w[(b * 32 + c) * 6 + s];
    lgt[t * 6 + s] = 1.f / (1.f + expf(-a));
  }
  __syncthreads();
  if (tid < 36) {
    int p = tid / 6, s = tid - p * 6;
    float a = 0.f;
#pragma unroll
    for (int t2 = 0; t2 < 6; ++t2) a += tatv[p * 6 + t2] * lgt[t2 * 6 + s];
    lg2w[(b * 6 + p) * 6 + s] = a;
  }
}

// ---------------- K5c: BN1 + softmax -> Tc ----------------
__global__ __launch_bounds__(128) void k_coefs(const float* __restrict__ lg2w,
    const float* __restrict__ bn1g, const float* __restrict__ bn1b, float* __restrict__ tcw) {
  __shared__ float mu[6], iv[6], gg[6], bb[6];
  int tid = threadIdx.x;
  if (tid < 6) {
    float s = 0.f, sq = 0.f;
    for (int b = 0; b < 16; ++b)
      for (int q = 0; q < 6; ++q) {
        float v = lg2w[(b * 6 + q) * 6 + tid];
        s += v; sq += v * v;
      }
    float m = s / 96.f;
    mu[tid] = m;
    iv[tid] = rsqrtf(sq / 96.f - m * m + 1e-5f);
    gg[tid] = bn1g[tid]; bb[tid] = bn1b[tid];
  }
  __syncthreads();
  for (int idx = tid; idx < 96; idx += 128) {
    int b = idx / 6, q = idx - b * 6;
    float v[6], mx = -1e30f;
#pragma unroll
    for (int l = 0; l < 6; ++l) {
      v[l] = (lg2w[(b * 6 + q) * 6 + l] - mu[l]) * iv[l] * gg[l] + bb[l];
      mx = fmaxf(mx, v[l]);
    }
    float tot = 0.f;
#pragma unroll
    for (int l = 0; l < 6; ++l) { v[l] = expf(v[l] - mx); tot += v[l]; }
    float inv = 1.f / tot;
#pragma unroll
    for (int l = 0; l < 6; ++l) tcw[(b * 6 + l) * 6 + q] = v[l] * inv;
  }
}

// ---------------- K6a: xo = leaky(g2@Tc)+res6, per-c sum/sumsq ----------------
__global__ __launch_bounds__(256) void k_xo(const float* __restrict__ g2w,
    const float* __restrict__ res6, const float* __restrict__ tcw,
    float* __restrict__ xow, float* __restrict__ stats) {
  __shared__ float Tcl[36];
  __shared__ float redS[32][8], redQ[32][8];
  int b = blockIdx.x, chunk = blockIdx.y, tid = threadIdx.x;
  if (tid < 36) Tcl[tid] = tcw[b * 36 + tid];
  __syncthreads();
  int c = tid & 31, sub = tid >> 5;
  int n0 = chunk * 50;
  float s = 0.f, sq = 0.f;
  for (int idx = sub; idx < 300; idx += 8) {
    int nl = idx / 6, q = idx - nl * 6;
    int n = n0 + nl;
    int base = ((b * 32 + c) * 500 + n) * 6;
    const float* gp = g2w + base;
    float xv = 0.f;
#pragma unroll
    for (int l = 0; l < 6; ++l) xv += gp[l] * Tcl[l * 6 + q];
    xv = xv > 0.f ? xv : 0.01f * xv;
    xv += res6[base + q];
    xow[base + q] = xv;
    s += xv; sq += xv * xv;
  }
  redS[c][sub] = s; redQ[c][sub] = sq;
  __syncthreads();
  if (sub == 0) {
    float ts = 0.f, tq = 0.f;
#pragma unroll
    for (int k = 0; k < 8; ++k) { ts += redS[c][k]; tq += redQ[c][k]; }
    atomicAdd(&stats[c], ts);
    atomicAdd(&stats[32 + c], tq);
  }
}

// ---------------- K6b: BN2 normalize -> FP32 out ----------------
__global__ __launch_bounds__(256) void k_out(const float* __restrict__ xow,
    const float* __restrict__ stats, const float* __restrict__ g2c, const float* __restrict__ b2c,
    float* __restrict__ out) {
  int base = (blockIdx.x * 256 + threadIdx.x) * 4;
#pragma unroll
  for (int k = 0; k < 4; ++k) {
    int i = base + k;
    int c = (i / 3000) & 31;
    float m = stats[c] * (1.f / 48000.f);
    float var = stats[32 + c] * (1.f / 48000.f) - m * m;
    out[i] = (xow[i] - m) * rsqrtf(var + 1e-5f) * g2c[c] + b2c[c];
  }
}

extern "C" void kernel_launch(void* const* d_in, const int* in_sizes, int n_in,
                              void* d_out, int out_size, void* d_ws, size_t ws_size,
                              hipStream_t stream)
{
  (void)in_sizes; (void)out_size;

  float* ws = (float*)d_ws;
  float* Af   = ws;                 // 250,000
  float* Wf   = Af + 250000;        // 65,536 (65,322 used)
  float* A2   = Wf + 65536;         // 250,000
  float* h3x  = A2 + 250000;        // 2,560,000 (B,T,N,32)
  float* z1x  = h3x + 2560000;
  float* z2x  = z1x + 2560000;
  float* z3x  = z2x + 2560000;
  float* z4x  = z3x + 2560000;
  float* res6 = z4x + 2560000;      // 1,536,000
  float* g2w  = res6 + 1536000;     // 1,536,000
  float* f1w  = g2w + 1536000;      // 48,000
  float* f2w  = f1w + 48000;        // 3,072
  float* lg2w = f2w + 3072;         // 576
  float* tcw  = lg2w + 576;         // 576
  float* stats= tcw + 576;          // 64
  int*   dtf  = (int*)(stats + 64); // 1 int
  float* xf   = z4x;                // x fp32 overlay: dead after k_front, before k_attn2#2
  float* xow  = z1x;                // reuse z1 region after k_mlp
  u16*   Abf  = (u16*)g2w;          // 512x512 bf16 A pack (g2w region dead until k_mlp)
  u16*   A2bf = (u16*)(g2w + 131072); // 512x512 bf16 A2 pack
  // frontend weight packs overlay the A2 fp32 region (dead after k_pk)
  u32*   qkp  = (u32*)A2;           // 12288 u32
  float* te1T = A2 + 12288;         // 2048
  float* lvT  = A2 + 14336;         // 4096
  float* loT  = A2 + 18432;         // 4096
  float* te2T = A2 + 22528;         // 2048
  float* c1T  = A2 + 24576;         // 1024 (end 25600 < 250000)
  if (ws_size < (size_t)16489952 * sizeof(float)) return;  // workspace guard

  // converted-weight offsets inside Wf (cumulative over dict inputs 2..28)
  const float* c1W  = Wf + 0;
  const float* c1B  = Wf + 1024;
  const float* te1W = Wf + 1056;
  const float* te1B = Wf + 3104;
  const float* qW   = Wf + 3168;
  const float* qB   = Wf + 15456;
  const float* kW   = Wf + 15520;
  const float* kB   = Wf + 27808;
  const float* lvW  = Wf + 27872;
  const float* lvB  = Wf + 31968;
  const float* loW  = Wf + 32032;
  const float* loB  = Wf + 36128;
  const float* te2W = Wf + 36192;
  const float* te2B = Wf + 38240;
  const float* mlpW = Wf + 38272;
  const float* mlpB = Wf + 48512;
  const float* ct1W = Wf + 48576;
  const float* ct1B = Wf + 48636;
  const float* tc1W = Wf + 48642;
  const float* tc2W = Wf + 48674;
  const float* tatw = Wf + 49174;
  const float* tatb = Wf + 65174;
  const float* tatv = Wf + 65210;
  const float* bn1g = Wf + 65246;
  const float* bn1b = Wf + 65252;
  const float* bn2g = Wf + 65258;
  const float* bn2b = Wf + 65290;

  Ptrs ps;
  for (int i = 0; i < 29; ++i) ps.p[i] = (i < n_in) ? d_in[i] : d_in[0];

  hipMemsetAsync(stats, 0, 64 * sizeof(float), stream);
  k_resolve<<<dim3(1),     64, 0, stream>>>(ps.p[25], dtf);
  k_cvt  <<<dim3(1232),    256, 0, stream>>>(ps, dtf, Af, Wf);
  k_cvtx <<<dim3(10000),   256, 0, stream>>>(ps.p[0], dtf, xf);
  k_a2   <<<dim3(2, 63),   256, 0, stream>>>(Af, A2);
  k_pk   <<<dim3(1024),    256, 0, stream>>>(Af, A2, Abf, A2bf);
  k_wpack<<<dim3(100),     256, 0, stream>>>(qW, kW, te1W, lvW, loW, te2W, c1W,
                                             qkp, te1T, lvT, loT, te2T, c1T);
  k_front<<<dim3(125, 16), 256, 0, stream>>>(xf, qkp, te1T, lvT, loT, te2T, c1T,
                                             c1B, te1B, qB, kB, lvB, loB, te2B,
                                             h3x, res6);
  k_z12m <<<dim3(160, 8),  256, 0, stream>>>(h3x, Abf, A2bf, z1x, z2x);
  k_attn2<<<dim3(160, 8),  256, 0, stream>>>(h3x, h3x, z3x);
  k_attn2<<<dim3(160, 8),  256, 0, stream>>>(h3x, z3x, z4x);
  k_mlp  <<<dim3(16, 16),  256, 0, stream>>>(h3x, z1x, z2x, z3x, z4x, mlpW, mlpB,
                                             ct1W, ct1B, g2w);
  k_f1n  <<<dim3(188),     256, 0, stream>>>(g2w, tc1W, f1w);
  k_f2   <<<dim3(512),      64, 0, stream>>>(g2w, tc2W, f2w);
  k_tatt <<<dim3(16),      256, 0, stream>>>(f1w, tatw, f2w, tatb, tatv, lg2w);
  k_coefs<<<dim3(1),       128, 0, stream>>>(lg2w, bn1g, bn1b, tcw);
  k_xo   <<<dim3(16, 10),  256, 0, stream>>>(g2w, res6, tcw, xow, stats);
  k_out  <<<dim3(1500),    256, 0, stream>>>(xow, stats, bn2g, bn2b, (float*)d_out);
}